// Round 3
// baseline (283.941 us; speedup 1.0000x reference)
//
#include <hip/hip_runtime.h>
#include <hip/hip_bf16.h>

// Problem constants
#define BB 2
#define TT 2048
#define CC 768
#define HH 12
#define DD 64
#define NQKV 2304           // 3*H*D
#define MTOT (BB*TT)        // 4096

typedef __bf16 bf16x8 __attribute__((ext_vector_type(8)));
typedef __bf16 bf16x4 __attribute__((ext_vector_type(4)));
typedef float  f32x4  __attribute__((ext_vector_type(4)));

__device__ __forceinline__ f32x4 mfma16(bf16x8 a, bf16x8 b, f32x4 c) {
    return __builtin_amdgcn_mfma_f32_16x16x32_bf16(a, b, c, 0, 0, 0);
}

// ---------------------------------------------------------------------------
// 1) f32 -> bf16 convert for x, w_attn, w_proj (one fused elementwise kernel)
// ---------------------------------------------------------------------------
__global__ __launch_bounds__(256) void cvt_bf16_kernel(
    const float* __restrict__ x, const float* __restrict__ wa, const float* __restrict__ wp,
    __bf16* __restrict__ xb, __bf16* __restrict__ wab, __bf16* __restrict__ wpb)
{
    const long NX = (long)MTOT * CC;       // 3,145,728
    const long NWA = (long)NQKV * CC;      // 1,769,472
    long idx = ((long)blockIdx.x * 256 + threadIdx.x) * 4;
    const float* src; __bf16* dst; long off;
    if (idx < NX)            { src = x;  dst = xb;  off = idx; }
    else if (idx < NX + NWA) { src = wa; dst = wab; off = idx - NX; }
    else                     { src = wp; dst = wpb; off = idx - NX - NWA; }
    float4 v = *(const float4*)(src + off);
    bf16x4 o;
    o[0] = (__bf16)v.x; o[1] = (__bf16)v.y; o[2] = (__bf16)v.z; o[3] = (__bf16)v.w;
    *(bf16x4*)(dst + off) = o;
}

// ---------------------------------------------------------------------------
// 2) NT GEMM (A[M,K] row-major, B[N,K] row-major), 128x128 tile, BK=32,
//    bf16 MFMA 16x16x32. EPI=0: QKV epilogue (scatter to q,k,vT bf16).
//    EPI=1: proj epilogue (f32 out).
// ---------------------------------------------------------------------------
template<int EPI>
__global__ __launch_bounds__(256, 2) void gemm_nt_kernel(
    const __bf16* __restrict__ A, const __bf16* __restrict__ Bw,
    const float* __restrict__ bias,
    __bf16* __restrict__ oQ, __bf16* __restrict__ oK, __bf16* __restrict__ oVT,
    float* __restrict__ oOut, int K)
{
    __shared__ __align__(16) __bf16 As[128 * 32];
    __shared__ __align__(16) __bf16 Bs[128 * 32];
    const int tid = threadIdx.x;
    const int m0 = blockIdx.y * 128, n0 = blockIdx.x * 128;
    const int w = tid >> 6, lane = tid & 63, quad = lane >> 4, l16 = lane & 15;
    const int wm = (w >> 1) * 64, wn = (w & 1) * 64;
    const int sr = tid >> 2, scc = (tid & 3) * 8;   // staging row / col

    f32x4 acc[4][4] = {};

    for (int kt = 0; kt < K; kt += 32) {
        __syncthreads();
        *(uint4*)(As + sr * 32 + scc)        = *(const uint4*)(A  + (long)(m0 + sr) * K      + kt + scc);
        *(uint4*)(As + (sr + 64) * 32 + scc) = *(const uint4*)(A  + (long)(m0 + sr + 64) * K + kt + scc);
        *(uint4*)(Bs + sr * 32 + scc)        = *(const uint4*)(Bw + (long)(n0 + sr) * K      + kt + scc);
        *(uint4*)(Bs + (sr + 64) * 32 + scc) = *(const uint4*)(Bw + (long)(n0 + sr + 64) * K + kt + scc);
        __syncthreads();

        bf16x8 af[4], bfr[4];
#pragma unroll
        for (int g = 0; g < 4; g++)  af[g]  = *(const bf16x8*)(As + (wm + g * 16 + l16) * 32 + quad * 8);
#pragma unroll
        for (int jb = 0; jb < 4; jb++) bfr[jb] = *(const bf16x8*)(Bs + (wn + jb * 16 + l16) * 32 + quad * 8);
#pragma unroll
        for (int g = 0; g < 4; g++)
#pragma unroll
            for (int jb = 0; jb < 4; jb++)
                acc[g][jb] = mfma16(af[g], bfr[jb], acc[g][jb]);
    }

    // epilogue: C/D layout col = lane&15, row = quad*4 + reg
#pragma unroll
    for (int jb = 0; jb < 4; jb++) {
        const int n = n0 + wn + jb * 16 + l16;
        const float bv = bias[n];
#pragma unroll
        for (int g = 0; g < 4; g++) {
#pragma unroll
            for (int r = 0; r < 4; r++) {
                const int m = m0 + wm + g * 16 + quad * 4 + r;
                const float v = acc[g][jb][r] + bv;
                if (EPI == 0) {
                    const int which = n / 768;
                    const int rem = n - which * 768;
                    const int h = rem >> 6, d = rem & 63;
                    const int b = m >> 11, t = m & 2047;
                    const __bf16 hv = (__bf16)v;
                    if (which == 0)      oQ [(((b * HH + h) * TT + t) << 6) + d] = hv;
                    else if (which == 1) oK [(((b * HH + h) * TT + t) << 6) + d] = hv;
                    else                 oVT[((((b * HH + h) << 6) + d) * TT) + t] = hv;
                } else {
                    oOut[(long)m * CC + n] = v;
                }
            }
        }
    }
}

// ---------------------------------------------------------------------------
// 3) Head-0 selection scores: S[b,i,j] = (1<=j<i) ? relu(q0_i . k0_j * 0.125) : 0
// ---------------------------------------------------------------------------
__global__ __launch_bounds__(256) void sgemm_kernel(
    const __bf16* __restrict__ q, const __bf16* __restrict__ k, float* __restrict__ S)
{
    const int tj = blockIdx.x, ti = blockIdx.y, b = blockIdx.z;
    if (tj > ti) return;
    const int w = threadIdx.x >> 6, lane = threadIdx.x & 63, quad = lane >> 4, l16 = lane & 15;
    const int i0 = ti * 64 + w * 16;

    const __bf16* qp = q + (((long)(b * HH + 0) * TT + i0 + l16) << 6) + quad * 8;
    bf16x8 a0 = *(const bf16x8*)qp, a1 = *(const bf16x8*)(qp + 32);
    const __bf16* kbase = k + ((long)(b * HH + 0) * TT << 6);

#pragma unroll
    for (int jb = 0; jb < 4; jb++) {
        const __bf16* kp = kbase + (((long)(tj * 64 + jb * 16 + l16)) << 6) + quad * 8;
        bf16x8 b0 = *(const bf16x8*)kp, b1 = *(const bf16x8*)(kp + 32);
        f32x4 acc = {};
        acc = mfma16(a0, b0, acc);
        acc = mfma16(a1, b1, acc);
        const int j = tj * 64 + jb * 16 + l16;
#pragma unroll
        for (int r = 0; r < 4; r++) {
            const int i = i0 + quad * 4 + r;
            float v = fmaxf(acc[r] * 0.125f, 0.0f);
            v = (j >= 1 && j < i) ? v : 0.0f;
            S[((long)b * TT + i) * TT + j] = v;
        }
    }
}

// ---------------------------------------------------------------------------
// 4) Exclusive cumsum over query dim (axis i), per column j: 2-pass chunked.
// ---------------------------------------------------------------------------
__global__ __launch_bounds__(256) void scan_sum_kernel(
    const float* __restrict__ S, float* __restrict__ csum)
{
    const int j = blockIdx.x * 256 + threadIdx.x;
    const int chunk = blockIdx.y, b = blockIdx.z;
    const int ib = chunk * 128;
    const float* p = S + ((long)b * TT + ib) * TT + j;
    float s = 0.0f;
#pragma unroll 4
    for (int ii = 0; ii < 128; ii++) {
        float v = p[(long)ii * TT];
        s += ((ib + ii) > j) ? v : 0.0f;
    }
    csum[(b * 16 + chunk) * TT + j] = s;
}

__global__ __launch_bounds__(256) void scan_write_kernel(
    float* __restrict__ S, const float* __restrict__ csum)
{
    const int j = blockIdx.x * 256 + threadIdx.x;
    const int chunk = blockIdx.y, b = blockIdx.z;
    const int ib = chunk * 128;
    float off = 0.0f;
    for (int c = 0; c < chunk; c++) off += csum[(b * 16 + c) * TT + j];
    float* p = S + ((long)b * TT + ib) * TT + j;
#pragma unroll 4
    for (int ii = 0; ii < 128; ii++) {
        float v = p[(long)ii * TT];
        v = ((ib + ii) > j) ? v : 0.0f;
        p[(long)ii * TT] = off;    // exclusive: write before add
        off += v;
    }
}

// ---------------------------------------------------------------------------
// 5) Flash attention with F subtraction. v3:
//    - balanced q-tile mapping (constant work/block) as v2.
//    - FIFO-aware software pipeline: per iter the vmem issue order is
//        [QK mfma (waits K-cur, retires F-cur)] [F-sub: free]
//        [issue V-cur] [issue F-next] [issue K-next]
//        [softmax overlaps V] [PV waits V only -> F/K-next stay in flight]
//      so the long-latency F loads (L3) get a full iteration in flight.
// ---------------------------------------------------------------------------
__global__ __launch_bounds__(256, 3) void flash_kernel(
    const __bf16* __restrict__ q, const __bf16* __restrict__ k, const __bf16* __restrict__ vT,
    const float* __restrict__ F, __bf16* __restrict__ y)
{
    __shared__ __align__(16) __bf16 Pls[4][16 * 72];   // per-wave 16x64 P tile, stride 72
    const int bid = blockIdx.x, h = blockIdx.y, b = blockIdx.z;
    const int w = threadIdx.x >> 6, lane = threadIdx.x & 63, quad = lane >> 4, l16 = lane & 15;
    int qt;
    if      (w == 0) qt = bid;
    else if (w == 1) qt = 63 - bid;
    else if (w == 2) qt = 64 + bid;
    else             qt = 127 - bid;
    const int i0 = qt * 16;
    const int jmax = i0 + 15;

    const __bf16* qp = q + (((long)(b * HH + h) * TT + i0 + l16) << 6) + quad * 8;
    const bf16x8 aq0 = *(const bf16x8*)qp;
    const bf16x8 aq1 = *(const bf16x8*)(qp + 32);
    const __bf16* kb = k  + ((long)(b * HH + h) * TT << 6);
    const __bf16* vb = vT + ((long)(b * HH + h) * TT << 6);
    const float*  Fb = F  + (long)b * TT * TT + (long)i0 * TT;   // rows of this q-tile
    __bf16* Pl = &Pls[w][0];

    f32x4 O[4] = {};
    float mr[4], lr[4];
#pragma unroll
    for (int r = 0; r < 4; r++) { mr[r] = -1e30f; lr[r] = 0.0f; }

    // --- preload tile 0: F first, then K (QK's K-wait retires F via FIFO) ---
    float Fn[4][4];
#pragma unroll
    for (int jh = 0; jh < 4; jh++)
#pragma unroll
        for (int r = 0; r < 4; r++)
            Fn[jh][r] = Fb[(long)(quad * 4 + r) * TT + jh * 16 + l16];

    bf16x8 kc0[4], kc1[4];
#pragma unroll
    for (int jh = 0; jh < 4; jh++) {
        const __bf16* kp = kb + (((long)(jh * 16 + l16)) << 6) + quad * 8;
        kc0[jh] = *(const bf16x8*)kp;
        kc1[jh] = *(const bf16x8*)(kp + 32);
    }

    for (int jt = 0; jt <= jmax; jt += 64) {
        // ---- 1. QK MFMAs on the prefetched K tile (drains F-cur too) ----
        float sc[4][4];
#pragma unroll
        for (int jh = 0; jh < 4; jh++) {
            f32x4 acc = {};
            acc = mfma16(aq0, kc0[jh], acc);
            acc = mfma16(aq1, kc1[jh], acc);
#pragma unroll
            for (int r = 0; r < 4; r++) sc[jh][r] = acc[r];
        }
        // ---- 2. F subtraction + causal mask (Fn already landed) ----
        const bool masked = (jt + 63 > i0);
#pragma unroll
        for (int jh = 0; jh < 4; jh++) {
            const int j = jt + jh * 16 + l16;
#pragma unroll
            for (int r = 0; r < 4; r++) {
                const int i = i0 + quad * 4 + r;
                float v = fmaf(sc[jh][r], 0.125f, -Fn[jh][r]);
                if (masked) v = (j <= i) ? v : -1e30f;
                sc[jh][r] = v;
            }
        }
        // ---- 3a. issue V(cur) ----
        bf16x8 vv0[4], vv1[4];
#pragma unroll
        for (int db = 0; db < 4; db++) {
            const __bf16* vp = vb + ((long)(db * 16 + l16) * TT) + jt + quad * 8;
            vv0[db] = *(const bf16x8*)vp;
            vv1[db] = *(const bf16x8*)(vp + 32);
        }
        // ---- 3b. issue F(next) (clamped redundant reload on last iter) ----
        const int jn = (jt + 64 <= jmax) ? jt + 64 : jt;
#pragma unroll
        for (int jh = 0; jh < 4; jh++)
#pragma unroll
            for (int r = 0; r < 4; r++)
                Fn[jh][r] = Fb[(long)(quad * 4 + r) * TT + jn + jh * 16 + l16];
        // ---- 3c. issue K(next) ----
#pragma unroll
        for (int jh = 0; jh < 4; jh++) {
            const __bf16* kp = kb + (((long)(jn + jh * 16 + l16)) << 6) + quad * 8;
            kc0[jh] = *(const bf16x8*)kp;
            kc1[jh] = *(const bf16x8*)(kp + 32);
        }
        // ---- 4. online softmax (row stats across the 16 lanes of each quad) ----
        float al[4];
#pragma unroll
        for (int r = 0; r < 4; r++) {
            float t = fmaxf(fmaxf(sc[0][r], sc[1][r]), fmaxf(sc[2][r], sc[3][r]));
#pragma unroll
            for (int off = 8; off >= 1; off >>= 1) t = fmaxf(t, __shfl_xor(t, off, 16));
            const float mn = fmaxf(mr[r], t);
            al[r] = __expf(mr[r] - mn);
            mr[r] = mn;
            float su = 0.0f;
#pragma unroll
            for (int jh = 0; jh < 4; jh++) {
                const float p = __expf(sc[jh][r] - mn);
                sc[jh][r] = p;
                su += p;
            }
#pragma unroll
            for (int off = 8; off >= 1; off >>= 1) su += __shfl_xor(su, off, 16);
            lr[r] = lr[r] * al[r] + su;
        }
#pragma unroll
        for (int db = 0; db < 4; db++) {
            O[db][0] *= al[0]; O[db][1] *= al[1]; O[db][2] *= al[2]; O[db][3] *= al[3];
        }
        // ---- 5. P -> LDS (C-layout -> row-major [i][j]), wave-private ----
#pragma unroll
        for (int r = 0; r < 4; r++) {
            const int il = quad * 4 + r;
#pragma unroll
            for (int jh = 0; jh < 4; jh++)
                Pl[il * 72 + jh * 16 + l16] = (__bf16)sc[jh][r];
        }
        const bf16x8 ap0 = *(const bf16x8*)(Pl + l16 * 72 + quad * 8);
        const bf16x8 ap1 = *(const bf16x8*)(Pl + l16 * 72 + 32 + quad * 8);
        // ---- 6. PV (waits V only; F/K-next remain in flight) ----
#pragma unroll
        for (int db = 0; db < 4; db++) {
            O[db] = mfma16(ap0, vv0[db], O[db]);
            O[db] = mfma16(ap1, vv1[db], O[db]);
        }
    }

    float inv[4];
#pragma unroll
    for (int r = 0; r < 4; r++) inv[r] = 1.0f / lr[r];
#pragma unroll
    for (int db = 0; db < 4; db++) {
#pragma unroll
        for (int r = 0; r < 4; r++) {
            const int i = i0 + quad * 4 + r;
            y[((long)(b * TT + i)) * (HH * DD) + h * 64 + db * 16 + l16] = (__bf16)(O[db][r] * inv[r]);
        }
    }
}

// ---------------------------------------------------------------------------
extern "C" void kernel_launch(void* const* d_in, const int* in_sizes, int n_in,
                              void* d_out, int out_size, void* d_ws, size_t ws_size,
                              hipStream_t stream)
{
    const float* x      = (const float*)d_in[0];
    const float* w_attn = (const float*)d_in[1];
    const float* b_attn = (const float*)d_in[2];
    const float* w_proj = (const float*)d_in[3];
    const float* b_proj = (const float*)d_in[4];
    float* out = (float*)d_out;

    char* ws = (char*)d_ws;
    __bf16* xb  = (__bf16*)ws; ws += (long)MTOT * CC * 2;          // 6,291,456
    __bf16* wab = (__bf16*)ws; ws += (long)NQKV * CC * 2;          // 3,538,944
    __bf16* wpb = (__bf16*)ws; ws += (long)CC * (HH*DD) * 2;       // 1,179,648
    __bf16* qb  = (__bf16*)ws; ws += (long)BB * HH * TT * DD * 2;  // 6,291,456
    __bf16* kb  = (__bf16*)ws; ws += (long)BB * HH * TT * DD * 2;
    __bf16* vtb = (__bf16*)ws; ws += (long)BB * HH * TT * DD * 2;
    float*  SF  = (float*)ws;  ws += (long)BB * TT * TT * 4;       // 33,554,432
    float*  cs  = (float*)ws;  ws += (long)BB * 16 * TT * 4;       // 262,144
    __bf16* yb  = (__bf16*)ws; ws += (long)MTOT * (HH*DD) * 2;     // 6,291,456

    // 1) convert inputs to bf16
    cvt_bf16_kernel<<<5376, 256, 0, stream>>>(x, w_attn, w_proj, xb, wab, wpb);
    // 2) QKV projection -> q, k, vT (bf16)
    gemm_nt_kernel<0><<<dim3(NQKV / 128, MTOT / 128), 256, 0, stream>>>(
        xb, wab, b_attn, qb, kb, vtb, nullptr, CC);
    // 3) head-0 selection scores S
    sgemm_kernel<<<dim3(TT / 64, TT / 64, BB), 256, 0, stream>>>(qb, kb, SF);
    // 4) exclusive cumsum over query dim -> F (in place)
    scan_sum_kernel<<<dim3(TT / 256, 16, BB), 256, 0, stream>>>(SF, cs);
    scan_write_kernel<<<dim3(TT / 256, 16, BB), 256, 0, stream>>>(SF, cs);
    // 5) flash attention with F subtraction -> y (bf16)
    flash_kernel<<<dim3(32, HH, BB), 256, 0, stream>>>(qb, kb, vtb, SF, yb);
    // 6) output projection -> out (f32)
    gemm_nt_kernel<1><<<dim3((HH*DD) / 128, MTOT / 128), 256, 0, stream>>>(
        yb, wpb, b_proj, nullptr, nullptr, nullptr, out, HH * DD);
}

// Round 4
// 269.767 us; speedup vs baseline: 1.0525x; 1.0525x over previous
//
#include <hip/hip_runtime.h>
#include <hip/hip_bf16.h>

// Problem constants
#define BB 2
#define TT 2048
#define CC 768
#define HH 12
#define DD 64
#define NQKV 2304           // 3*H*D
#define MTOT (BB*TT)        // 4096
#define CH 32               // scan chunk rows
#define NCH (TT/CH)         // 64 chunks

typedef __bf16 bf16x8 __attribute__((ext_vector_type(8)));
typedef __bf16 bf16x4 __attribute__((ext_vector_type(4)));
typedef float  f32x4  __attribute__((ext_vector_type(4)));

__device__ __forceinline__ f32x4 mfma16(bf16x8 a, bf16x8 b, f32x4 c) {
    return __builtin_amdgcn_mfma_f32_16x16x32_bf16(a, b, c, 0, 0, 0);
}

__device__ __forceinline__ void load_lds16(const void* g, void* l) {
    __builtin_amdgcn_global_load_lds(
        (const __attribute__((address_space(1))) void*)g,
        (__attribute__((address_space(3))) void*)l, 16, 0, 0);
}

// ---------------------------------------------------------------------------
// 1) f32 -> bf16 convert for x, w_attn, w_proj
// ---------------------------------------------------------------------------
__global__ __launch_bounds__(256) void cvt_bf16_kernel(
    const float* __restrict__ x, const float* __restrict__ wa, const float* __restrict__ wp,
    __bf16* __restrict__ xb, __bf16* __restrict__ wab, __bf16* __restrict__ wpb)
{
    const long NX = (long)MTOT * CC;       // 3,145,728
    const long NWA = (long)NQKV * CC;      // 1,769,472
    long idx = ((long)blockIdx.x * 256 + threadIdx.x) * 4;
    const float* src; __bf16* dst; long off;
    if (idx < NX)            { src = x;  dst = xb;  off = idx; }
    else if (idx < NX + NWA) { src = wa; dst = wab; off = idx - NX; }
    else                     { src = wp; dst = wpb; off = idx - NX - NWA; }
    float4 v = *(const float4*)(src + off);
    bf16x4 o;
    o[0] = (__bf16)v.x; o[1] = (__bf16)v.y; o[2] = (__bf16)v.z; o[3] = (__bf16)v.w;
    *(bf16x4*)(dst + off) = o;
}

// ---------------------------------------------------------------------------
// 2) NT GEMM (A[M,K] row-major, B[N,K] row-major), 128x128 tile, BK=32,
//    global_load_lds width-16 staging (m97 pattern).
// ---------------------------------------------------------------------------
template<int EPI>
__global__ __launch_bounds__(256, 2) void gemm_nt_kernel(
    const __bf16* __restrict__ A, const __bf16* __restrict__ Bw,
    const float* __restrict__ bias,
    __bf16* __restrict__ oQ, __bf16* __restrict__ oK, __bf16* __restrict__ oVT,
    float* __restrict__ oOut, int K)
{
    __shared__ __align__(16) __bf16 As[128 * 32];
    __shared__ __align__(16) __bf16 Bs[128 * 32];
    const int tid = threadIdx.x;
    const int m0 = blockIdx.y * 128, n0 = blockIdx.x * 128;
    const int w = tid >> 6, lane = tid & 63, quad = lane >> 4, l16 = lane & 15;
    const int wm = (w >> 1) * 64, wn = (w & 1) * 64;
    // global_load_lds staging: wave w covers rows w*16..w*16+15 of the tile;
    // lane l -> row w*16 + (l>>2), col elems (l&3)*8; LDS dst = wave base + l*16B
    const int grow = w * 16 + (lane >> 2);
    const int gcol = (lane & 3) * 8;
    __bf16* AsW = As + w * 512;
    __bf16* BsW = Bs + w * 512;

    f32x4 acc[4][4] = {};

    for (int kt = 0; kt < K; kt += 32) {
        __syncthreads();
        load_lds16(A  + (long)(m0 + grow) * K + kt + gcol,      AsW);
        load_lds16(A  + (long)(m0 + grow + 64) * K + kt + gcol, AsW + 2048);
        load_lds16(Bw + (long)(n0 + grow) * K + kt + gcol,      BsW);
        load_lds16(Bw + (long)(n0 + grow + 64) * K + kt + gcol, BsW + 2048);
        __syncthreads();

        bf16x8 af[4], bfr[4];
#pragma unroll
        for (int g = 0; g < 4; g++)  af[g]  = *(const bf16x8*)(As + (wm + g * 16 + l16) * 32 + quad * 8);
#pragma unroll
        for (int jb = 0; jb < 4; jb++) bfr[jb] = *(const bf16x8*)(Bs + (wn + jb * 16 + l16) * 32 + quad * 8);
#pragma unroll
        for (int g = 0; g < 4; g++)
#pragma unroll
            for (int jb = 0; jb < 4; jb++)
                acc[g][jb] = mfma16(af[g], bfr[jb], acc[g][jb]);
    }

    // epilogue: C/D layout col = lane&15, row = quad*4 + reg
#pragma unroll
    for (int jb = 0; jb < 4; jb++) {
        const int n = n0 + wn + jb * 16 + l16;
        const float bv = bias[n];
#pragma unroll
        for (int g = 0; g < 4; g++) {
#pragma unroll
            for (int r = 0; r < 4; r++) {
                const int m = m0 + wm + g * 16 + quad * 4 + r;
                const float v = acc[g][jb][r] + bv;
                if (EPI == 0) {
                    const int which = n / 768;
                    const int rem = n - which * 768;
                    const int h = rem >> 6, d = rem & 63;
                    const int b = m >> 11, t = m & 2047;
                    const __bf16 hv = (__bf16)v;
                    if (which == 0)      oQ [(((b * HH + h) * TT + t) << 6) + d] = hv;
                    else if (which == 1) oK [(((b * HH + h) * TT + t) << 6) + d] = hv;
                    else                 oVT[((((b * HH + h) << 6) + d) * TT) + t] = hv;
                } else {
                    oOut[(long)m * CC + n] = v;
                }
            }
        }
    }
}

// ---------------------------------------------------------------------------
// 3) Head-0 selection scores: S[b,i,j] = (1<=j<i) ? relu(q0_i . k0_j * 0.125) : 0
// ---------------------------------------------------------------------------
__global__ __launch_bounds__(256) void sgemm_kernel(
    const __bf16* __restrict__ q, const __bf16* __restrict__ k, float* __restrict__ S)
{
    const int tj = blockIdx.x, ti = blockIdx.y, b = blockIdx.z;
    if (tj > ti) return;
    const int w = threadIdx.x >> 6, lane = threadIdx.x & 63, quad = lane >> 4, l16 = lane & 15;
    const int i0 = ti * 64 + w * 16;

    const __bf16* qp = q + (((long)(b * HH + 0) * TT + i0 + l16) << 6) + quad * 8;
    bf16x8 a0 = *(const bf16x8*)qp, a1 = *(const bf16x8*)(qp + 32);
    const __bf16* kbase = k + ((long)(b * HH + 0) * TT << 6);

#pragma unroll
    for (int jb = 0; jb < 4; jb++) {
        const __bf16* kp = kbase + (((long)(tj * 64 + jb * 16 + l16)) << 6) + quad * 8;
        bf16x8 b0 = *(const bf16x8*)kp, b1 = *(const bf16x8*)(kp + 32);
        f32x4 acc = {};
        acc = mfma16(a0, b0, acc);
        acc = mfma16(a1, b1, acc);
        const int j = tj * 64 + jb * 16 + l16;
#pragma unroll
        for (int r = 0; r < 4; r++) {
            const int i = i0 + quad * 4 + r;
            float v = fmaxf(acc[r] * 0.125f, 0.0f);
            v = (j >= 1 && j < i) ? v : 0.0f;
            S[((long)b * TT + i) * TT + j] = v;
        }
    }
}

// ---------------------------------------------------------------------------
// 4) Exclusive cumsum over query dim, per column j: 3-pass chunked (CH=32).
// ---------------------------------------------------------------------------
__global__ __launch_bounds__(256) void scan_sum_kernel(
    const float* __restrict__ S, float* __restrict__ csum)
{
    const int j = blockIdx.x * 256 + threadIdx.x;
    const int chunk = blockIdx.y, b = blockIdx.z;
    const int ib = chunk * CH;
    const float* p = S + ((long)b * TT + ib) * TT + j;
    float s = 0.0f;
#pragma unroll
    for (int ii = 0; ii < CH; ii++) {
        float v = p[(long)ii * TT];
        s += ((ib + ii) > j) ? v : 0.0f;
    }
    csum[(b * NCH + chunk) * TT + j] = s;
}

__global__ __launch_bounds__(256) void scan_prefix_kernel(float* __restrict__ csum)
{
    const int idx = blockIdx.x * 256 + threadIdx.x;   // 4096 threads
    const int b = idx >> 11, j = idx & 2047;
    float vals[NCH];
#pragma unroll
    for (int c = 0; c < NCH; c++) vals[c] = csum[(b * NCH + c) * TT + j];
    float off = 0.0f;
#pragma unroll
    for (int c = 0; c < NCH; c++) { float t = vals[c]; vals[c] = off; off += t; }
#pragma unroll
    for (int c = 0; c < NCH; c++) csum[(b * NCH + c) * TT + j] = vals[c];
}

__global__ __launch_bounds__(256) void scan_write_kernel(
    float* __restrict__ S, const float* __restrict__ csum)
{
    const int j = blockIdx.x * 256 + threadIdx.x;
    const int chunk = blockIdx.y, b = blockIdx.z;
    const int ib = chunk * CH;
    float off = csum[(b * NCH + chunk) * TT + j];
    float* p = S + ((long)b * TT + ib) * TT + j;
#pragma unroll
    for (int ii = 0; ii < CH; ii++) {
        float v = p[(long)ii * TT];
        v = ((ib + ii) > j) ? v : 0.0f;
        p[(long)ii * TT] = off;    // exclusive: write before add
        off += v;
    }
}

// ---------------------------------------------------------------------------
// 5) Flash attention with F subtraction. v4: FIXED-BASE softmax.
//    Scores = qk*0.125 - F with F>=0 and F[:,0]==0 (BOS-protected), so every
//    row has max in [~-3,~+3]: p = exp(min(s,60)) is safe without a running
//    max. No per-iter shuffle reductions, no O-rescale. l reduced once at end.
// ---------------------------------------------------------------------------
__global__ __launch_bounds__(256, 3) void flash_kernel(
    const __bf16* __restrict__ q, const __bf16* __restrict__ k, const __bf16* __restrict__ vT,
    const float* __restrict__ F, __bf16* __restrict__ y)
{
    __shared__ __align__(16) __bf16 Pls[4][16 * 72];   // per-wave 16x64 P tile, stride 72
    const int bid = blockIdx.x, h = blockIdx.y, b = blockIdx.z;
    const int w = threadIdx.x >> 6, lane = threadIdx.x & 63, quad = lane >> 4, l16 = lane & 15;
    int qt;
    if      (w == 0) qt = bid;
    else if (w == 1) qt = 63 - bid;
    else if (w == 2) qt = 64 + bid;
    else             qt = 127 - bid;
    const int i0 = qt * 16;
    const int jmax = i0 + 15;

    const __bf16* qp = q + (((long)(b * HH + h) * TT + i0 + l16) << 6) + quad * 8;
    const bf16x8 aq0 = *(const bf16x8*)qp;
    const bf16x8 aq1 = *(const bf16x8*)(qp + 32);
    const __bf16* kb = k  + ((long)(b * HH + h) * TT << 6);
    const __bf16* vb = vT + ((long)(b * HH + h) * TT << 6);
    const float*  Fb = F  + (long)b * TT * TT + (long)i0 * TT;
    __bf16* Pl = &Pls[w][0];

    f32x4 O[4] = {};
    float lr[4] = {0.0f, 0.0f, 0.0f, 0.0f};

    // --- preload tile 0: F first, then K (QK's K-wait retires F via FIFO) ---
    float Fn[4][4];
#pragma unroll
    for (int jh = 0; jh < 4; jh++)
#pragma unroll
        for (int r = 0; r < 4; r++)
            Fn[jh][r] = Fb[(long)(quad * 4 + r) * TT + jh * 16 + l16];

    bf16x8 kc0[4], kc1[4];
#pragma unroll
    for (int jh = 0; jh < 4; jh++) {
        const __bf16* kp = kb + (((long)(jh * 16 + l16)) << 6) + quad * 8;
        kc0[jh] = *(const bf16x8*)kp;
        kc1[jh] = *(const bf16x8*)(kp + 32);
    }

    for (int jt = 0; jt <= jmax; jt += 64) {
        // ---- 1. QK MFMAs on the prefetched K tile (drains F-cur too) ----
        float sc[4][4];
#pragma unroll
        for (int jh = 0; jh < 4; jh++) {
            f32x4 acc = {};
            acc = mfma16(aq0, kc0[jh], acc);
            acc = mfma16(aq1, kc1[jh], acc);
#pragma unroll
            for (int r = 0; r < 4; r++) sc[jh][r] = acc[r];
        }
        // ---- 2. issue V(cur), F(next), K(next) while VALU works below ----
        bf16x8 vv0[4], vv1[4];
#pragma unroll
        for (int db = 0; db < 4; db++) {
            const __bf16* vp = vb + ((long)(db * 16 + l16) * TT) + jt + quad * 8;
            vv0[db] = *(const bf16x8*)vp;
            vv1[db] = *(const bf16x8*)(vp + 32);
        }
        float Fc[4][4];
#pragma unroll
        for (int jh = 0; jh < 4; jh++)
#pragma unroll
            for (int r = 0; r < 4; r++)
                Fc[jh][r] = Fn[jh][r];
        const int jn = (jt + 64 <= jmax) ? jt + 64 : jt;
#pragma unroll
        for (int jh = 0; jh < 4; jh++)
#pragma unroll
            for (int r = 0; r < 4; r++)
                Fn[jh][r] = Fb[(long)(quad * 4 + r) * TT + jn + jh * 16 + l16];
#pragma unroll
        for (int jh = 0; jh < 4; jh++) {
            const __bf16* kp = kb + (((long)(jn + jh * 16 + l16)) << 6) + quad * 8;
            kc0[jh] = *(const bf16x8*)kp;
            kc1[jh] = *(const bf16x8*)(kp + 32);
        }
        __builtin_amdgcn_sched_barrier(0);   // pin: loads above must issue here
        // ---- 3. F-sub + mask + exp + l-accum (no reductions!) ----
        const bool masked = (jt + 63 > i0);
#pragma unroll
        for (int jh = 0; jh < 4; jh++) {
            const int j = jt + jh * 16 + l16;
            float su = 0.0f;
#pragma unroll
            for (int r = 0; r < 4; r++) {
                const int i = i0 + quad * 4 + r;
                float v = fmaf(sc[jh][r], 0.125f, -Fc[jh][r]);
                if (masked) v = (j <= i) ? v : -1e30f;
                const float p = __expf(fminf(v, 60.0f));
                sc[jh][r] = p;
                lr[r] += p;
            }
        }
        // ---- 4. P -> LDS (C-layout -> row-major [i][j]), wave-private ----
#pragma unroll
        for (int r = 0; r < 4; r++) {
            const int il = quad * 4 + r;
#pragma unroll
            for (int jh = 0; jh < 4; jh++)
                Pl[il * 72 + jh * 16 + l16] = (__bf16)sc[jh][r];
        }
        const bf16x8 ap0 = *(const bf16x8*)(Pl + l16 * 72 + quad * 8);
        const bf16x8 ap1 = *(const bf16x8*)(Pl + l16 * 72 + 32 + quad * 8);
        // ---- 5. PV (waits V only; F/K-next remain in flight) ----
#pragma unroll
        for (int db = 0; db < 4; db++) {
            O[db] = mfma16(ap0, vv0[db], O[db]);
            O[db] = mfma16(ap1, vv1[db], O[db]);
        }
    }

    // one-time l reduction across the 16 lanes of each quad-row-group
    float inv[4];
#pragma unroll
    for (int r = 0; r < 4; r++) {
        float s = lr[r];
#pragma unroll
        for (int off = 8; off >= 1; off >>= 1) s += __shfl_xor(s, off, 16);
        inv[r] = 1.0f / s;
    }
#pragma unroll
    for (int db = 0; db < 4; db++) {
#pragma unroll
        for (int r = 0; r < 4; r++) {
            const int i = i0 + quad * 4 + r;
            y[((long)(b * TT + i)) * (HH * DD) + h * 64 + db * 16 + l16] = (__bf16)(O[db][r] * inv[r]);
        }
    }
}

// ---------------------------------------------------------------------------
extern "C" void kernel_launch(void* const* d_in, const int* in_sizes, int n_in,
                              void* d_out, int out_size, void* d_ws, size_t ws_size,
                              hipStream_t stream)
{
    const float* x      = (const float*)d_in[0];
    const float* w_attn = (const float*)d_in[1];
    const float* b_attn = (const float*)d_in[2];
    const float* w_proj = (const float*)d_in[3];
    const float* b_proj = (const float*)d_in[4];
    float* out = (float*)d_out;

    char* ws = (char*)d_ws;
    __bf16* xb  = (__bf16*)ws; ws += (long)MTOT * CC * 2;
    __bf16* wab = (__bf16*)ws; ws += (long)NQKV * CC * 2;
    __bf16* wpb = (__bf16*)ws; ws += (long)CC * (HH*DD) * 2;
    __bf16* qb  = (__bf16*)ws; ws += (long)BB * HH * TT * DD * 2;
    __bf16* kb  = (__bf16*)ws; ws += (long)BB * HH * TT * DD * 2;
    __bf16* vtb = (__bf16*)ws; ws += (long)BB * HH * TT * DD * 2;
    float*  SF  = (float*)ws;  ws += (long)BB * TT * TT * 4;
    float*  cs  = (float*)ws;  ws += (long)BB * NCH * TT * 4;
    __bf16* yb  = (__bf16*)ws; ws += (long)MTOT * (HH*DD) * 2;

    // 1) convert inputs to bf16
    cvt_bf16_kernel<<<5376, 256, 0, stream>>>(x, w_attn, w_proj, xb, wab, wpb);
    // 2) QKV projection -> q, k, vT (bf16)
    gemm_nt_kernel<0><<<dim3(NQKV / 128, MTOT / 128), 256, 0, stream>>>(
        xb, wab, b_attn, qb, kb, vtb, nullptr, CC);
    // 3) head-0 selection scores S
    sgemm_kernel<<<dim3(TT / 64, TT / 64, BB), 256, 0, stream>>>(qb, kb, SF);
    // 4) exclusive cumsum over query dim -> F (in place), 3-pass
    scan_sum_kernel<<<dim3(TT / 256, NCH, BB), 256, 0, stream>>>(SF, cs);
    scan_prefix_kernel<<<16, 256, 0, stream>>>(cs);
    scan_write_kernel<<<dim3(TT / 256, NCH, BB), 256, 0, stream>>>(SF, cs);
    // 5) flash attention with F subtraction -> y (bf16)
    flash_kernel<<<dim3(32, HH, BB), 256, 0, stream>>>(qb, kb, vtb, SF, yb);
    // 6) output projection -> out (f32)
    gemm_nt_kernel<1><<<dim3((HH*DD) / 128, MTOT / 128), 256, 0, stream>>>(
        yb, wpb, b_proj, nullptr, nullptr, nullptr, out, HH * DD);
}

// Round 5
// 227.987 us; speedup vs baseline: 1.2454x; 1.1833x over previous
//
#include <hip/hip_runtime.h>
#include <hip/hip_bf16.h>

// Problem constants
#define BB 2
#define TT 2048
#define CC 768
#define HH 12
#define DD 64
#define NQKV 2304           // 3*H*D
#define MTOT (BB*TT)        // 4096
#define CH 32               // scan chunk rows
#define NCH (TT/CH)         // 64 chunks

typedef __bf16 bf16x8 __attribute__((ext_vector_type(8)));
typedef __bf16 bf16x4 __attribute__((ext_vector_type(4)));
typedef float  f32x4  __attribute__((ext_vector_type(4)));

__device__ __forceinline__ f32x4 mfma16(bf16x8 a, bf16x8 b, f32x4 c) {
    return __builtin_amdgcn_mfma_f32_16x16x32_bf16(a, b, c, 0, 0, 0);
}

__device__ __forceinline__ void load_lds16(const void* g, void* l) {
    __builtin_amdgcn_global_load_lds(
        (const __attribute__((address_space(1))) void*)g,
        (__attribute__((address_space(3))) void*)l, 16, 0, 0);
}

// ---------------------------------------------------------------------------
// 1) f32 -> bf16 convert for x, w_attn, w_proj
// ---------------------------------------------------------------------------
__global__ __launch_bounds__(256) void cvt_bf16_kernel(
    const float* __restrict__ x, const float* __restrict__ wa, const float* __restrict__ wp,
    __bf16* __restrict__ xb, __bf16* __restrict__ wab, __bf16* __restrict__ wpb)
{
    const long NX = (long)MTOT * CC;       // 3,145,728
    const long NWA = (long)NQKV * CC;      // 1,769,472
    long idx = ((long)blockIdx.x * 256 + threadIdx.x) * 4;
    const float* src; __bf16* dst; long off;
    if (idx < NX)            { src = x;  dst = xb;  off = idx; }
    else if (idx < NX + NWA) { src = wa; dst = wab; off = idx - NX; }
    else                     { src = wp; dst = wpb; off = idx - NX - NWA; }
    float4 v = *(const float4*)(src + off);
    bf16x4 o;
    o[0] = (__bf16)v.x; o[1] = (__bf16)v.y; o[2] = (__bf16)v.z; o[3] = (__bf16)v.w;
    *(bf16x4*)(dst + off) = o;
}

// ---------------------------------------------------------------------------
// 2) NT GEMM (A[M,K] row-major, B[N,K] row-major), 128x128 tile, BK=32,
//    global_load_lds width-16 staging (m97 pattern).
// ---------------------------------------------------------------------------
template<int EPI>
__global__ __launch_bounds__(256, 2) void gemm_nt_kernel(
    const __bf16* __restrict__ A, const __bf16* __restrict__ Bw,
    const float* __restrict__ bias,
    __bf16* __restrict__ oQ, __bf16* __restrict__ oK, __bf16* __restrict__ oVT,
    float* __restrict__ oOut, int K)
{
    __shared__ __align__(16) __bf16 As[128 * 32];
    __shared__ __align__(16) __bf16 Bs[128 * 32];
    const int tid = threadIdx.x;
    const int m0 = blockIdx.y * 128, n0 = blockIdx.x * 128;
    const int w = tid >> 6, lane = tid & 63, quad = lane >> 4, l16 = lane & 15;
    const int wm = (w >> 1) * 64, wn = (w & 1) * 64;
    const int grow = w * 16 + (lane >> 2);
    const int gcol = (lane & 3) * 8;
    __bf16* AsW = As + w * 512;
    __bf16* BsW = Bs + w * 512;

    f32x4 acc[4][4] = {};

    for (int kt = 0; kt < K; kt += 32) {
        __syncthreads();
        load_lds16(A  + (long)(m0 + grow) * K + kt + gcol,      AsW);
        load_lds16(A  + (long)(m0 + grow + 64) * K + kt + gcol, AsW + 2048);
        load_lds16(Bw + (long)(n0 + grow) * K + kt + gcol,      BsW);
        load_lds16(Bw + (long)(n0 + grow + 64) * K + kt + gcol, BsW + 2048);
        __syncthreads();

        bf16x8 af[4], bfr[4];
#pragma unroll
        for (int g = 0; g < 4; g++)  af[g]  = *(const bf16x8*)(As + (wm + g * 16 + l16) * 32 + quad * 8);
#pragma unroll
        for (int jb = 0; jb < 4; jb++) bfr[jb] = *(const bf16x8*)(Bs + (wn + jb * 16 + l16) * 32 + quad * 8);
#pragma unroll
        for (int g = 0; g < 4; g++)
#pragma unroll
            for (int jb = 0; jb < 4; jb++)
                acc[g][jb] = mfma16(af[g], bfr[jb], acc[g][jb]);
    }

    // epilogue: C/D layout col = lane&15, row = quad*4 + reg
#pragma unroll
    for (int jb = 0; jb < 4; jb++) {
        const int n = n0 + wn + jb * 16 + l16;
        const float bv = bias[n];
#pragma unroll
        for (int g = 0; g < 4; g++) {
#pragma unroll
            for (int r = 0; r < 4; r++) {
                const int m = m0 + wm + g * 16 + quad * 4 + r;
                const float v = acc[g][jb][r] + bv;
                if (EPI == 0) {
                    const int which = n / 768;
                    const int rem = n - which * 768;
                    const int h = rem >> 6, d = rem & 63;
                    const int b = m >> 11, t = m & 2047;
                    const __bf16 hv = (__bf16)v;
                    if (which == 0)      oQ [(((b * HH + h) * TT + t) << 6) + d] = hv;
                    else if (which == 1) oK [(((b * HH + h) * TT + t) << 6) + d] = hv;
                    else                 oVT[((((b * HH + h) << 6) + d) * TT) + t] = hv;
                } else {
                    oOut[(long)m * CC + n] = v;
                }
            }
        }
    }
}

// ---------------------------------------------------------------------------
// 3) Head-0 selection scores: S[b,i,j] = (1<=j<i) ? relu(q0_i . k0_j * 0.125) : 0
// ---------------------------------------------------------------------------
__global__ __launch_bounds__(256) void sgemm_kernel(
    const __bf16* __restrict__ q, const __bf16* __restrict__ k, float* __restrict__ S)
{
    const int tj = blockIdx.x, ti = blockIdx.y, b = blockIdx.z;
    if (tj > ti) return;
    const int w = threadIdx.x >> 6, lane = threadIdx.x & 63, quad = lane >> 4, l16 = lane & 15;
    const int i0 = ti * 64 + w * 16;

    const __bf16* qp = q + (((long)(b * HH + 0) * TT + i0 + l16) << 6) + quad * 8;
    bf16x8 a0 = *(const bf16x8*)qp, a1 = *(const bf16x8*)(qp + 32);
    const __bf16* kbase = k + ((long)(b * HH + 0) * TT << 6);

#pragma unroll
    for (int jb = 0; jb < 4; jb++) {
        const __bf16* kp = kbase + (((long)(tj * 64 + jb * 16 + l16)) << 6) + quad * 8;
        bf16x8 b0 = *(const bf16x8*)kp, b1 = *(const bf16x8*)(kp + 32);
        f32x4 acc = {};
        acc = mfma16(a0, b0, acc);
        acc = mfma16(a1, b1, acc);
        const int j = tj * 64 + jb * 16 + l16;
#pragma unroll
        for (int r = 0; r < 4; r++) {
            const int i = i0 + quad * 4 + r;
            float v = fmaxf(acc[r] * 0.125f, 0.0f);
            v = (j >= 1 && j < i) ? v : 0.0f;
            S[((long)b * TT + i) * TT + j] = v;
        }
    }
}

// ---------------------------------------------------------------------------
// 4) Exclusive cumsum over query dim, per column j: 3-pass chunked (CH=32).
// ---------------------------------------------------------------------------
__global__ __launch_bounds__(256) void scan_sum_kernel(
    const float* __restrict__ S, float* __restrict__ csum)
{
    const int j = blockIdx.x * 256 + threadIdx.x;
    const int chunk = blockIdx.y, b = blockIdx.z;
    const int ib = chunk * CH;
    const float* p = S + ((long)b * TT + ib) * TT + j;
    float s = 0.0f;
#pragma unroll
    for (int ii = 0; ii < CH; ii++) {
        float v = p[(long)ii * TT];
        s += ((ib + ii) > j) ? v : 0.0f;
    }
    csum[(b * NCH + chunk) * TT + j] = s;
}

__global__ __launch_bounds__(256) void scan_prefix_kernel(float* __restrict__ csum)
{
    const int idx = blockIdx.x * 256 + threadIdx.x;   // 4096 threads
    const int b = idx >> 11, j = idx & 2047;
    float vals[NCH];
#pragma unroll
    for (int c = 0; c < NCH; c++) vals[c] = csum[(b * NCH + c) * TT + j];
    float off = 0.0f;
#pragma unroll
    for (int c = 0; c < NCH; c++) { float t = vals[c]; vals[c] = off; off += t; }
#pragma unroll
    for (int c = 0; c < NCH; c++) csum[(b * NCH + c) * TT + j] = vals[c];
}

__global__ __launch_bounds__(256) void scan_write_kernel(
    float* __restrict__ S, const float* __restrict__ csum)
{
    const int j = blockIdx.x * 256 + threadIdx.x;
    const int chunk = blockIdx.y, b = blockIdx.z;
    const int ib = chunk * CH;
    float off = csum[(b * NCH + chunk) * TT + j];
    float* p = S + ((long)b * TT + ib) * TT + j;
#pragma unroll
    for (int ii = 0; ii < CH; ii++) {
        float v = p[(long)ii * TT];
        v = ((ib + ii) > j) ? v : 0.0f;
        p[(long)ii * TT] = off;    // exclusive: write before add
        off += v;
    }
}

// ---------------------------------------------------------------------------
// 5) Flash attention with F subtraction. v5: SHARED K/V LDS STAGING.
//    Block = one 64-row q-block (4 waves x 16 rows). K/V tiles staged once
//    per block into LDS via global_load_lds with XOR swizzle
//    (slot = colblk ^ (row&7)) -> DMA-compatible AND conflict-free b128 reads.
//    Global bytes/block-iter: K 8K + V 8K + F 16K = 32KB for 4 waves of work
//    (2.5x less than v4's per-wave loads). Causal imbalance: big-qt-first.
//    Fixed-base softmax (scores bounded; F>=0, col0 F=0).
// ---------------------------------------------------------------------------
__global__ __launch_bounds__(256, 3) void flash_kernel(
    const __bf16* __restrict__ q, const __bf16* __restrict__ k, const __bf16* __restrict__ vT,
    const float* __restrict__ F, __bf16* __restrict__ y)
{
    __shared__ __align__(16) __bf16 Ks[64 * 64];       // [keyrow][d], XOR-swizzled 16B slots
    __shared__ __align__(16) __bf16 Vs[64 * 64];       // [d][keycol], XOR-swizzled 16B slots
    __shared__ __align__(16) __bf16 Pls[4][16 * 72];   // per-wave P tile, stride 72
    const int qt = 31 - blockIdx.x;                    // big-first for LPT scheduling
    const int h = blockIdx.y, b = blockIdx.z;
    const int w = threadIdx.x >> 6, lane = threadIdx.x & 63, quad = lane >> 4, l16 = lane & 15;
    const int i0 = qt * 64 + w * 16;

    const __bf16* qp = q + (((long)(b * HH + h) * TT + i0 + l16) << 6) + quad * 8;
    const bf16x8 aq0 = *(const bf16x8*)qp;
    const bf16x8 aq1 = *(const bf16x8*)(qp + 32);
    const __bf16* kb = k  + ((long)(b * HH + h) * TT << 6);
    const __bf16* vb = vT + ((long)(b * HH + h) * TT << 6);
    const float*  Fb = F  + (long)b * TT * TT + (long)i0 * TT;
    __bf16* Pl = &Pls[w][0];

    // DMA source swizzle: lane l covers LDS slot (row rl = l>>3, slot cs = l&7);
    // slot cs holds global col-block cs ^ (rl&7).
    const int rl = lane >> 3;                 // 0..7
    const int cs8 = ((lane & 7) ^ rl) * 8;    // swizzled global col offset (elems)
    __bf16* KsW = Ks + w * 1024;              // wave w stages rows w*16..w*16+15
    __bf16* VsW = Vs + w * 1024;
    // reader swizzle: logical (row, colblk cb) lives at slot cb ^ (row&7)
    const int sw0 = ((quad)     ^ (l16 & 7)) * 8;
    const int sw1 = ((quad + 4) ^ (l16 & 7)) * 8;

    f32x4 O[4] = {};
    float lr[4] = {0.0f, 0.0f, 0.0f, 0.0f};

    // F prefetch (tile 0)
    float Fn[4][4];
#pragma unroll
    for (int jh = 0; jh < 4; jh++)
#pragma unroll
        for (int r = 0; r < 4; r++)
            Fn[jh][r] = Fb[(long)(quad * 4 + r) * TT + jh * 16 + l16];

    const int jtend = qt * 64;
    for (int jt = 0; jt <= jtend; jt += 64) {
        __syncthreads();   // prev iter's LDS reads done
        // ---- DMA stage K,V tile (this wave: 16 K-rows, 16 V-d-rows) ----
        load_lds16(kb + ((long)(jt + w * 16 + rl) << 6) + cs8,     KsW);
        load_lds16(kb + ((long)(jt + w * 16 + 8 + rl) << 6) + cs8, KsW + 512);
        load_lds16(vb + (long)(w * 16 + rl) * TT + jt + cs8,       VsW);
        load_lds16(vb + (long)(w * 16 + 8 + rl) * TT + jt + cs8,   VsW + 512);
        // ---- F: cur <- prefetched, issue next (consumed next iter) ----
        float Fc[4][4];
#pragma unroll
        for (int jh = 0; jh < 4; jh++)
#pragma unroll
            for (int r = 0; r < 4; r++)
                Fc[jh][r] = Fn[jh][r];
        const int jn = (jt + 64 <= jtend) ? jt + 64 : jt;
#pragma unroll
        for (int jh = 0; jh < 4; jh++)
#pragma unroll
            for (int r = 0; r < 4; r++)
                Fn[jh][r] = Fb[(long)(quad * 4 + r) * TT + jn + jh * 16 + l16];
        __builtin_amdgcn_sched_barrier(0);   // pin load issue before barrier
        __syncthreads();   // staging complete (drains DMA + F-cur already landed)
        // ---- QK MFMAs from LDS ----
        float sc[4][4];
#pragma unroll
        for (int jh = 0; jh < 4; jh++) {
            const bf16x8 kc0 = *(const bf16x8*)(Ks + ((jh * 16 + l16) << 6) + sw0);
            const bf16x8 kc1 = *(const bf16x8*)(Ks + ((jh * 16 + l16) << 6) + sw1);
            f32x4 acc = {};
            acc = mfma16(aq0, kc0, acc);
            acc = mfma16(aq1, kc1, acc);
#pragma unroll
            for (int r = 0; r < 4; r++) sc[jh][r] = acc[r];
        }
        // ---- F-sub + mask + exp + l-accum ----
        const bool masked = (jt + 63 > i0);
#pragma unroll
        for (int jh = 0; jh < 4; jh++) {
            const int j = jt + jh * 16 + l16;
#pragma unroll
            for (int r = 0; r < 4; r++) {
                const int i = i0 + quad * 4 + r;
                float v = fmaf(sc[jh][r], 0.125f, -Fc[jh][r]);
                if (masked) v = (j <= i) ? v : -1e30f;
                const float p = __expf(fminf(v, 60.0f));
                sc[jh][r] = p;
                lr[r] += p;
            }
        }
        // ---- P -> LDS (C-layout -> row-major [i][j]), wave-private ----
#pragma unroll
        for (int r = 0; r < 4; r++) {
            const int il = quad * 4 + r;
#pragma unroll
            for (int jh = 0; jh < 4; jh++)
                Pl[il * 72 + jh * 16 + l16] = (__bf16)sc[jh][r];
        }
        const bf16x8 ap0 = *(const bf16x8*)(Pl + l16 * 72 + quad * 8);
        const bf16x8 ap1 = *(const bf16x8*)(Pl + l16 * 72 + 32 + quad * 8);
        // ---- PV from LDS V tile ----
#pragma unroll
        for (int db = 0; db < 4; db++) {
            const bf16x8 vv0 = *(const bf16x8*)(Vs + ((db * 16 + l16) << 6) + sw0);
            const bf16x8 vv1 = *(const bf16x8*)(Vs + ((db * 16 + l16) << 6) + sw1);
            O[db] = mfma16(ap0, vv0, O[db]);
            O[db] = mfma16(ap1, vv1, O[db]);
        }
    }

    // one-time l reduction across the 16 lanes of each quad-row-group
    float inv[4];
#pragma unroll
    for (int r = 0; r < 4; r++) {
        float s = lr[r];
#pragma unroll
        for (int off = 8; off >= 1; off >>= 1) s += __shfl_xor(s, off, 16);
        inv[r] = 1.0f / s;
    }
#pragma unroll
    for (int db = 0; db < 4; db++) {
#pragma unroll
        for (int r = 0; r < 4; r++) {
            const int i = i0 + quad * 4 + r;
            y[((long)(b * TT + i)) * (HH * DD) + h * 64 + db * 16 + l16] = (__bf16)(O[db][r] * inv[r]);
        }
    }
}

// ---------------------------------------------------------------------------
extern "C" void kernel_launch(void* const* d_in, const int* in_sizes, int n_in,
                              void* d_out, int out_size, void* d_ws, size_t ws_size,
                              hipStream_t stream)
{
    const float* x      = (const float*)d_in[0];
    const float* w_attn = (const float*)d_in[1];
    const float* b_attn = (const float*)d_in[2];
    const float* w_proj = (const float*)d_in[3];
    const float* b_proj = (const float*)d_in[4];
    float* out = (float*)d_out;

    char* ws = (char*)d_ws;
    __bf16* xb  = (__bf16*)ws; ws += (long)MTOT * CC * 2;
    __bf16* wab = (__bf16*)ws; ws += (long)NQKV * CC * 2;
    __bf16* wpb = (__bf16*)ws; ws += (long)CC * (HH*DD) * 2;
    __bf16* qb  = (__bf16*)ws; ws += (long)BB * HH * TT * DD * 2;
    __bf16* kb  = (__bf16*)ws; ws += (long)BB * HH * TT * DD * 2;
    __bf16* vtb = (__bf16*)ws; ws += (long)BB * HH * TT * DD * 2;
    float*  SF  = (float*)ws;  ws += (long)BB * TT * TT * 4;
    float*  cs  = (float*)ws;  ws += (long)BB * NCH * TT * 4;
    __bf16* yb  = (__bf16*)ws; ws += (long)MTOT * (HH*DD) * 2;

    // 1) convert inputs to bf16
    cvt_bf16_kernel<<<5376, 256, 0, stream>>>(x, w_attn, w_proj, xb, wab, wpb);
    // 2) QKV projection -> q, k, vT (bf16)
    gemm_nt_kernel<0><<<dim3(NQKV / 128, MTOT / 128), 256, 0, stream>>>(
        xb, wab, b_attn, qb, kb, vtb, nullptr, CC);
    // 3) head-0 selection scores S
    sgemm_kernel<<<dim3(TT / 64, TT / 64, BB), 256, 0, stream>>>(qb, kb, SF);
    // 4) exclusive cumsum over query dim -> F (in place), 3-pass
    scan_sum_kernel<<<dim3(TT / 256, NCH, BB), 256, 0, stream>>>(SF, cs);
    scan_prefix_kernel<<<16, 256, 0, stream>>>(cs);
    scan_write_kernel<<<dim3(TT / 256, NCH, BB), 256, 0, stream>>>(SF, cs);
    // 5) flash attention with F subtraction -> y (bf16)
    flash_kernel<<<dim3(32, HH, BB), 256, 0, stream>>>(qb, kb, vtb, SF, yb);
    // 6) output projection -> out (f32)
    gemm_nt_kernel<1><<<dim3((HH*DD) / 128, MTOT / 128), 256, 0, stream>>>(
        yb, wpb, b_proj, nullptr, nullptr, nullptr, out, HH * DD);
}

// Round 6
// 220.063 us; speedup vs baseline: 1.2903x; 1.0360x over previous
//
#include <hip/hip_runtime.h>
#include <hip/hip_bf16.h>

// Problem constants
#define BB 2
#define TT 2048
#define CC 768
#define HH 12
#define DD 64
#define NQKV 2304           // 3*H*D
#define MTOT (BB*TT)        // 4096
#define CH 32               // scan chunk rows
#define NCH (TT/CH)         // 64 chunks

typedef __bf16 bf16x8 __attribute__((ext_vector_type(8)));
typedef __bf16 bf16x4 __attribute__((ext_vector_type(4)));
typedef float  f32x4  __attribute__((ext_vector_type(4)));

__device__ __forceinline__ f32x4 mfma16(bf16x8 a, bf16x8 b, f32x4 c) {
    return __builtin_amdgcn_mfma_f32_16x16x32_bf16(a, b, c, 0, 0, 0);
}

__device__ __forceinline__ void load_lds16(const void* g, void* l) {
    __builtin_amdgcn_global_load_lds(
        (const __attribute__((address_space(1))) void*)g,
        (__attribute__((address_space(3))) void*)l, 16, 0, 0);
}

// ---------------------------------------------------------------------------
// 1) f32 -> bf16 convert for x, w_attn, w_proj
// ---------------------------------------------------------------------------
__global__ __launch_bounds__(256) void cvt_bf16_kernel(
    const float* __restrict__ x, const float* __restrict__ wa, const float* __restrict__ wp,
    __bf16* __restrict__ xb, __bf16* __restrict__ wab, __bf16* __restrict__ wpb)
{
    const long NX = (long)MTOT * CC;       // 3,145,728
    const long NWA = (long)NQKV * CC;      // 1,769,472
    long idx = ((long)blockIdx.x * 256 + threadIdx.x) * 4;
    const float* src; __bf16* dst; long off;
    if (idx < NX)            { src = x;  dst = xb;  off = idx; }
    else if (idx < NX + NWA) { src = wa; dst = wab; off = idx - NX; }
    else                     { src = wp; dst = wpb; off = idx - NX - NWA; }
    float4 v = *(const float4*)(src + off);
    bf16x4 o;
    o[0] = (__bf16)v.x; o[1] = (__bf16)v.y; o[2] = (__bf16)v.z; o[3] = (__bf16)v.w;
    *(bf16x4*)(dst + off) = o;
}

// ---------------------------------------------------------------------------
// 2) NT GEMM (A[M,K] row-major, B[N,K] row-major), 128x128 tile, BK=32,
//    global_load_lds width-16 staging (m97 pattern).
// ---------------------------------------------------------------------------
template<int EPI>
__global__ __launch_bounds__(256, 2) void gemm_nt_kernel(
    const __bf16* __restrict__ A, const __bf16* __restrict__ Bw,
    const float* __restrict__ bias,
    __bf16* __restrict__ oQ, __bf16* __restrict__ oK, __bf16* __restrict__ oVT,
    float* __restrict__ oOut, int K)
{
    __shared__ __align__(16) __bf16 As[128 * 32];
    __shared__ __align__(16) __bf16 Bs[128 * 32];
    const int tid = threadIdx.x;
    const int m0 = blockIdx.y * 128, n0 = blockIdx.x * 128;
    const int w = tid >> 6, lane = tid & 63, quad = lane >> 4, l16 = lane & 15;
    const int wm = (w >> 1) * 64, wn = (w & 1) * 64;
    const int grow = w * 16 + (lane >> 2);
    const int gcol = (lane & 3) * 8;
    __bf16* AsW = As + w * 512;
    __bf16* BsW = Bs + w * 512;

    f32x4 acc[4][4] = {};

    for (int kt = 0; kt < K; kt += 32) {
        __syncthreads();
        load_lds16(A  + (long)(m0 + grow) * K + kt + gcol,      AsW);
        load_lds16(A  + (long)(m0 + grow + 64) * K + kt + gcol, AsW + 2048);
        load_lds16(Bw + (long)(n0 + grow) * K + kt + gcol,      BsW);
        load_lds16(Bw + (long)(n0 + grow + 64) * K + kt + gcol, BsW + 2048);
        __syncthreads();

        bf16x8 af[4], bfr[4];
#pragma unroll
        for (int g = 0; g < 4; g++)  af[g]  = *(const bf16x8*)(As + (wm + g * 16 + l16) * 32 + quad * 8);
#pragma unroll
        for (int jb = 0; jb < 4; jb++) bfr[jb] = *(const bf16x8*)(Bs + (wn + jb * 16 + l16) * 32 + quad * 8);
#pragma unroll
        for (int g = 0; g < 4; g++)
#pragma unroll
            for (int jb = 0; jb < 4; jb++)
                acc[g][jb] = mfma16(af[g], bfr[jb], acc[g][jb]);
    }

    // epilogue: C/D layout col = lane&15, row = quad*4 + reg
#pragma unroll
    for (int jb = 0; jb < 4; jb++) {
        const int n = n0 + wn + jb * 16 + l16;
        const float bv = bias[n];
#pragma unroll
        for (int g = 0; g < 4; g++) {
#pragma unroll
            for (int r = 0; r < 4; r++) {
                const int m = m0 + wm + g * 16 + quad * 4 + r;
                const float v = acc[g][jb][r] + bv;
                if (EPI == 0) {
                    const int which = n / 768;
                    const int rem = n - which * 768;
                    const int h = rem >> 6, d = rem & 63;
                    const int b = m >> 11, t = m & 2047;
                    const __bf16 hv = (__bf16)v;
                    if (which == 0)      oQ [(((b * HH + h) * TT + t) << 6) + d] = hv;
                    else if (which == 1) oK [(((b * HH + h) * TT + t) << 6) + d] = hv;
                    else                 oVT[((((b * HH + h) << 6) + d) * TT) + t] = hv;
                } else {
                    oOut[(long)m * CC + n] = v;
                }
            }
        }
    }
}

// ---------------------------------------------------------------------------
// 3) Head-0 selection scores, bf16 out: S[b,i,j] = (1<=j<i) ? relu(qk*0.125) : 0
// ---------------------------------------------------------------------------
__global__ __launch_bounds__(256) void sgemm_kernel(
    const __bf16* __restrict__ q, const __bf16* __restrict__ k, __bf16* __restrict__ S)
{
    const int tj = blockIdx.x, ti = blockIdx.y, b = blockIdx.z;
    if (tj > ti) return;
    const int w = threadIdx.x >> 6, lane = threadIdx.x & 63, quad = lane >> 4, l16 = lane & 15;
    const int i0 = ti * 64 + w * 16;

    const __bf16* qp = q + (((long)(b * HH + 0) * TT + i0 + l16) << 6) + quad * 8;
    bf16x8 a0 = *(const bf16x8*)qp, a1 = *(const bf16x8*)(qp + 32);
    const __bf16* kbase = k + ((long)(b * HH + 0) * TT << 6);

#pragma unroll
    for (int jb = 0; jb < 4; jb++) {
        const __bf16* kp = kbase + (((long)(tj * 64 + jb * 16 + l16)) << 6) + quad * 8;
        bf16x8 b0 = *(const bf16x8*)kp, b1 = *(const bf16x8*)(kp + 32);
        f32x4 acc = {};
        acc = mfma16(a0, b0, acc);
        acc = mfma16(a1, b1, acc);
        const int j = tj * 64 + jb * 16 + l16;
#pragma unroll
        for (int r = 0; r < 4; r++) {
            const int i = i0 + quad * 4 + r;
            float v = fmaxf(acc[r] * 0.125f, 0.0f);
            v = (j >= 1 && j < i) ? v : 0.0f;
            S[((long)b * TT + i) * TT + j] = (__bf16)v;
        }
    }
}

// ---------------------------------------------------------------------------
// 4) Exclusive cumsum over query dim, per column j: 3-pass chunked (CH=32).
//    S bf16 in, F bf16 out (f32 accumulation).
// ---------------------------------------------------------------------------
__global__ __launch_bounds__(256) void scan_sum_kernel(
    const __bf16* __restrict__ S, float* __restrict__ csum)
{
    const int j = blockIdx.x * 256 + threadIdx.x;
    const int chunk = blockIdx.y, b = blockIdx.z;
    const int ib = chunk * CH;
    const __bf16* p = S + ((long)b * TT + ib) * TT + j;
    float s = 0.0f;
#pragma unroll
    for (int ii = 0; ii < CH; ii++) {
        float v = (float)p[(long)ii * TT];
        s += ((ib + ii) > j) ? v : 0.0f;
    }
    csum[(b * NCH + chunk) * TT + j] = s;
}

__global__ __launch_bounds__(256) void scan_prefix_kernel(float* __restrict__ csum)
{
    const int idx = blockIdx.x * 256 + threadIdx.x;   // 4096 threads
    const int b = idx >> 11, j = idx & 2047;
    float vals[NCH];
#pragma unroll
    for (int c = 0; c < NCH; c++) vals[c] = csum[(b * NCH + c) * TT + j];
    float off = 0.0f;
#pragma unroll
    for (int c = 0; c < NCH; c++) { float t = vals[c]; vals[c] = off; off += t; }
#pragma unroll
    for (int c = 0; c < NCH; c++) csum[(b * NCH + c) * TT + j] = vals[c];
}

__global__ __launch_bounds__(256) void scan_write_kernel(
    const __bf16* __restrict__ S, const float* __restrict__ csum, __bf16* __restrict__ Fo)
{
    const int j = blockIdx.x * 256 + threadIdx.x;
    const int chunk = blockIdx.y, b = blockIdx.z;
    const int ib = chunk * CH;
    float off = csum[(b * NCH + chunk) * TT + j];
    const __bf16* ps = S  + ((long)b * TT + ib) * TT + j;
    __bf16*       pf = Fo + ((long)b * TT + ib) * TT + j;
#pragma unroll
    for (int ii = 0; ii < CH; ii++) {
        float v = ((ib + ii) > j) ? (float)ps[(long)ii * TT] : 0.0f;
        pf[(long)ii * TT] = (__bf16)off;   // exclusive: write before add
        off += v;
    }
}

// ---------------------------------------------------------------------------
// 5) Flash attention with F subtraction. v6: PAIRED BLOCKS, bf16 F.
//    Block = 128 thr (2 waves x 16 q-rows = one 32-row tile per phase);
//    processes q-tile pair {bid, 63-bid} in two sequential phases ->
//    per-block work is CONSTANT (33-34 tiles): no drain tail, no resonance
//    (R5's grid.x=32 | 256 made each CU's 3 blocks identical-qt).
//    K/V staged once per block-iter into XOR-swizzled LDS via DMA.
//    Fixed-base softmax; mask only on the peeled diagonal tile.
// ---------------------------------------------------------------------------
__global__ __launch_bounds__(128, 2) void flash_kernel(
    const __bf16* __restrict__ q, const __bf16* __restrict__ k, const __bf16* __restrict__ vT,
    const __bf16* __restrict__ F, __bf16* __restrict__ y)
{
    __shared__ __align__(16) __bf16 Ks[64 * 64];
    __shared__ __align__(16) __bf16 Vs[64 * 64];
    __shared__ __align__(16) __bf16 Pls[2][16 * 72];
    const int bid = blockIdx.x, h = blockIdx.y, b = blockIdx.z;
    const int w = threadIdx.x >> 6, lane = threadIdx.x & 63, quad = lane >> 4, l16 = lane & 15;
    const int rl = lane >> 3;                 // DMA: row-in-group 0..7
    const int cs8 = ((lane & 7) ^ rl) * 8;    // DMA: swizzled source col offset
    __bf16* KsW = Ks + w * 2048;              // wave stages 32 rows
    __bf16* VsW = Vs + w * 2048;
    const int sw0 = ((quad)     ^ (l16 & 7)) * 8;   // reader swizzle
    const int sw1 = ((quad + 4) ^ (l16 & 7)) * 8;
    __bf16* Pl = &Pls[w][0];
    const __bf16* kb = k  + ((long)(b * HH + h) * TT << 6);
    const __bf16* vb = vT + ((long)(b * HH + h) * TT << 6);

    for (int ph = 0; ph < 2; ph++) {
        const int qt = ph ? (63 - bid) : bid;        // pair: constant total work
        const int i0 = qt * 32 + w * 16;
        const __bf16* qp = q + (((long)(b * HH + h) * TT + i0 + l16) << 6) + quad * 8;
        const bf16x8 aq0 = *(const bf16x8*)qp;
        const bf16x8 aq1 = *(const bf16x8*)(qp + 32);
        const __bf16* Fb = F + (long)b * TT * TT + (long)i0 * TT;
        f32x4 O[4] = {};
        float lr[4] = {0.0f, 0.0f, 0.0f, 0.0f};
        const int jtend = (qt >> 1) << 6;            // last (diagonal) tile

        for (int jt = 0; jt <= jtend; jt += 64) {
            __syncthreads();   // prev iter's LDS reads done
#pragma unroll
            for (int t = 0; t < 4; t++)
                load_lds16(kb + ((long)(jt + w * 32 + t * 8 + rl) << 6) + cs8, KsW + t * 512);
#pragma unroll
            for (int t = 0; t < 4; t++)
                load_lds16(vb + (long)(w * 32 + t * 8 + rl) * TT + jt + cs8, VsW + t * 512);
            // F loads: the barrier's vmcnt(0) drain covers them
            float Fc[4][4];
#pragma unroll
            for (int jh = 0; jh < 4; jh++)
#pragma unroll
                for (int r = 0; r < 4; r++)
                    Fc[jh][r] = (float)Fb[(long)(quad * 4 + r) * TT + jt + jh * 16 + l16];
            __syncthreads();   // staging + F visible
            // ---- QK from LDS ----
            float sc[4][4];
#pragma unroll
            for (int jh = 0; jh < 4; jh++) {
                const int jr = jh * 16 + l16;
                const bf16x8 kc0 = *(const bf16x8*)(Ks + (jr << 6) + sw0);
                const bf16x8 kc1 = *(const bf16x8*)(Ks + (jr << 6) + sw1);
                f32x4 acc = {};
                acc = mfma16(aq0, kc0, acc);
                acc = mfma16(aq1, kc1, acc);
#pragma unroll
                for (int r = 0; r < 4; r++) sc[jh][r] = acc[r];
            }
            // ---- softmax terms (mask only on diagonal tile; uniform branch) ----
            if (jt == jtend) {
#pragma unroll
                for (int jh = 0; jh < 4; jh++) {
                    const int j = jt + jh * 16 + l16;
#pragma unroll
                    for (int r = 0; r < 4; r++) {
                        const int i = i0 + quad * 4 + r;
                        float v = fmaf(sc[jh][r], 0.125f, -Fc[jh][r]);
                        v = (j <= i) ? v : -1e30f;
                        const float p = __expf(fminf(v, 60.0f));
                        sc[jh][r] = p;
                        lr[r] += p;
                    }
                }
            } else {
#pragma unroll
                for (int jh = 0; jh < 4; jh++) {
#pragma unroll
                    for (int r = 0; r < 4; r++) {
                        float v = fmaf(sc[jh][r], 0.125f, -Fc[jh][r]);
                        const float p = __expf(fminf(v, 60.0f));
                        sc[jh][r] = p;
                        lr[r] += p;
                    }
                }
            }
            // ---- P -> LDS (C-layout -> row-major), wave-private ----
#pragma unroll
            for (int r = 0; r < 4; r++) {
                const int il = quad * 4 + r;
#pragma unroll
                for (int jh = 0; jh < 4; jh++)
                    Pl[il * 72 + jh * 16 + l16] = (__bf16)sc[jh][r];
            }
            const bf16x8 ap0 = *(const bf16x8*)(Pl + l16 * 72 + quad * 8);
            const bf16x8 ap1 = *(const bf16x8*)(Pl + l16 * 72 + 32 + quad * 8);
            // ---- PV from LDS ----
#pragma unroll
            for (int db = 0; db < 4; db++) {
                const bf16x8 vv0 = *(const bf16x8*)(Vs + ((db * 16 + l16) << 6) + sw0);
                const bf16x8 vv1 = *(const bf16x8*)(Vs + ((db * 16 + l16) << 6) + sw1);
                O[db] = mfma16(ap0, vv0, O[db]);
                O[db] = mfma16(ap1, vv1, O[db]);
            }
        }

        float inv[4];
#pragma unroll
        for (int r = 0; r < 4; r++) {
            float s = lr[r];
#pragma unroll
            for (int off = 8; off >= 1; off >>= 1) s += __shfl_xor(s, off, 16);
            inv[r] = 1.0f / s;
        }
#pragma unroll
        for (int db = 0; db < 4; db++) {
#pragma unroll
            for (int r = 0; r < 4; r++) {
                const int i = i0 + quad * 4 + r;
                y[((long)(b * TT + i)) * (HH * DD) + h * 64 + db * 16 + l16] = (__bf16)(O[db][r] * inv[r]);
            }
        }
    }
}

// ---------------------------------------------------------------------------
extern "C" void kernel_launch(void* const* d_in, const int* in_sizes, int n_in,
                              void* d_out, int out_size, void* d_ws, size_t ws_size,
                              hipStream_t stream)
{
    const float* x      = (const float*)d_in[0];
    const float* w_attn = (const float*)d_in[1];
    const float* b_attn = (const float*)d_in[2];
    const float* w_proj = (const float*)d_in[3];
    const float* b_proj = (const float*)d_in[4];
    float* out = (float*)d_out;

    char* ws = (char*)d_ws;
    __bf16* xb  = (__bf16*)ws; ws += (long)MTOT * CC * 2;
    __bf16* wab = (__bf16*)ws; ws += (long)NQKV * CC * 2;
    __bf16* wpb = (__bf16*)ws; ws += (long)CC * (HH*DD) * 2;
    __bf16* qb  = (__bf16*)ws; ws += (long)BB * HH * TT * DD * 2;
    __bf16* kb  = (__bf16*)ws; ws += (long)BB * HH * TT * DD * 2;
    __bf16* vtb = (__bf16*)ws; ws += (long)BB * HH * TT * DD * 2;
    __bf16* SF  = (__bf16*)ws; ws += (long)BB * TT * TT * 2;       // S (bf16)
    __bf16* Fo  = (__bf16*)ws; ws += (long)BB * TT * TT * 2;       // F (bf16)
    float*  cs  = (float*)ws;  ws += (long)BB * NCH * TT * 4;
    __bf16* yb  = (__bf16*)ws; ws += (long)MTOT * (HH*DD) * 2;

    // 1) convert inputs to bf16
    cvt_bf16_kernel<<<5376, 256, 0, stream>>>(x, w_attn, w_proj, xb, wab, wpb);
    // 2) QKV projection -> q, k, vT (bf16)
    gemm_nt_kernel<0><<<dim3(NQKV / 128, MTOT / 128), 256, 0, stream>>>(
        xb, wab, b_attn, qb, kb, vtb, nullptr, CC);
    // 3) head-0 selection scores S (bf16)
    sgemm_kernel<<<dim3(TT / 64, TT / 64, BB), 256, 0, stream>>>(qb, kb, SF);
    // 4) exclusive cumsum over query dim -> F (bf16), 3-pass
    scan_sum_kernel<<<dim3(TT / 256, NCH, BB), 256, 0, stream>>>(SF, cs);
    scan_prefix_kernel<<<16, 256, 0, stream>>>(cs);
    scan_write_kernel<<<dim3(TT / 256, NCH, BB), 256, 0, stream>>>(SF, cs, Fo);
    // 5) flash attention with F subtraction -> y (bf16); paired q-tiles
    flash_kernel<<<dim3(32, HH, BB), 128, 0, stream>>>(qb, kb, vtb, Fo, yb);
    // 6) output projection -> out (f32)
    gemm_nt_kernel<1><<<dim3((HH*DD) / 128, MTOT / 128), 256, 0, stream>>>(
        yb, wpb, b_proj, nullptr, nullptr, nullptr, out, HH * DD);
}